// Round 10
// baseline (219.295 us; speedup 1.0000x reference)
//
#include <hip/hip_runtime.h>
#include <stdint.h>

typedef unsigned short u16;
typedef short bf16x8 __attribute__((ext_vector_type(8)));
typedef short bf16x4 __attribute__((ext_vector_type(4)));
typedef float f32x4 __attribute__((ext_vector_type(4)));

#define NN 384
#define DIMC 128
#define NPOS (NN*NN)
#define EPSV 1e-5f
#define LNS 136   // xn LDS row stride in u16

__device__ __forceinline__ u16 f2b(float f){
  union { float f; uint32_t u; } v; v.f = f;
  return (u16)((v.u + 0x7FFFu + ((v.u >> 16) & 1u)) >> 16);
}
__device__ __forceinline__ float b2f(u16 h){
  union { uint32_t u; float f; } v; v.u = ((uint32_t)h) << 16;
  return v.f;
}
__device__ __forceinline__ float sigm(float z){
  return __builtin_amdgcn_rcpf(1.0f + __expf(-z));
}

__device__ __forceinline__ void glds16(const u16* g, u16* l){
  __builtin_amdgcn_global_load_lds((const __attribute__((address_space(1))) void*)(g),
                                   (__attribute__((address_space(3))) void*)(l), 16, 0, 0);
}

// ---------------- kernel 0: fp32 -> bf16 weight conversion ----------------
__global__ void wconv_k(const float* __restrict__ s0, const float* __restrict__ s1,
                        const float* __restrict__ s2, const float* __restrict__ s3,
                        const float* __restrict__ s4, const float* __restrict__ s5,
                        u16* __restrict__ dst){
  int bid = blockIdx.x;
  int m = bid >> 6;
  int off = ((bid & 63) << 8) + threadIdx.x;
  const float* src = s0;
  if (m==1) src=s1; else if (m==2) src=s2; else if (m==3) src=s3;
  else if (m==4) src=s4; else if (m==5) src=s5;
  dst[(m<<14) + off] = f2b(src[off]);
}

// ---------------- kernel 1: LN + L/R projections (O-gate moved to phase3) ----------------
// block: fixed second-index c (j), 64 first-index rows r0..r0+63 (i), 4 waves.
// LN -> xn LDS; ALSO dumped to global xng[j][i][ch] (coalesced) for phase3's ogate GEMM.
// L/R passes: mfma(A=w, B=xn) -> D[e][p]; direct coalesced stores -> [e][j][k=i].
__global__ __launch_bounds__(256) void proj_k(
    const float* __restrict__ x, const float* __restrict__ nw, const float* __restrict__ nb,
    const u16* __restrict__ wb,
    const float* __restrict__ left_b, const float* __restrict__ lgate_b,
    const float* __restrict__ right_b, const float* __restrict__ rgate_b,
    u16* __restrict__ Lp, u16* __restrict__ Rp, u16* __restrict__ xng)
{
  __shared__ u16 xn[64*LNS];     // 17408 B
  const int tid = threadIdx.x, lane = tid & 63, wid = tid >> 6;
  const int bid = blockIdx.x;
  const int c = bid % NN, r0 = (bid / NN) * 64;
  const int l15 = lane & 15, lg = lane >> 4;

  // ---- LN: 16 lanes per position, 8 ch each ----
  {
    float4 w0 = *(const float4*)(nw + l15*8);
    float4 w1 = *(const float4*)(nw + l15*8 + 4);
    float4 bb0 = *(const float4*)(nb + l15*8);
    float4 bb1 = *(const float4*)(nb + l15*8 + 4);
    float4 v0[4], v1[4];
    #pragma unroll
    for (int it = 0; it < 4; ++it){
      int p = wid*16 + it*4 + lg;
      const float* xp = x + ((size_t)(r0 + p)*NN + c)*DIMC + l15*8;
      v0[it] = *(const float4*)xp;
      v1[it] = *(const float4*)(xp + 4);
    }
    #pragma unroll
    for (int it = 0; it < 4; ++it){
      int p = wid*16 + it*4 + lg;
      float s  = (v0[it].x+v0[it].y)+(v0[it].z+v0[it].w)+((v1[it].x+v1[it].y)+(v1[it].z+v1[it].w));
      float sq = v0[it].x*v0[it].x+v0[it].y*v0[it].y+v0[it].z*v0[it].z+v0[it].w*v0[it].w
               + v1[it].x*v1[it].x+v1[it].y*v1[it].y+v1[it].z*v1[it].z+v1[it].w*v1[it].w;
      #pragma unroll
      for (int o = 8; o; o >>= 1){ s += __shfl_xor(s, o); sq += __shfl_xor(sq, o); }
      float mean = s * (1.0f/128.0f);
      float var  = sq * (1.0f/128.0f) - mean*mean;
      float inv  = rsqrtf(var + EPSV);
      bf16x8 o8;
      o8[0] = (short)f2b((v0[it].x - mean)*inv*w0.x + bb0.x);
      o8[1] = (short)f2b((v0[it].y - mean)*inv*w0.y + bb0.y);
      o8[2] = (short)f2b((v0[it].z - mean)*inv*w0.z + bb0.z);
      o8[3] = (short)f2b((v0[it].w - mean)*inv*w0.w + bb0.w);
      o8[4] = (short)f2b((v1[it].x - mean)*inv*w1.x + bb1.x);
      o8[5] = (short)f2b((v1[it].y - mean)*inv*w1.y + bb1.y);
      o8[6] = (short)f2b((v1[it].z - mean)*inv*w1.z + bb1.z);
      o8[7] = (short)f2b((v1[it].w - mean)*inv*w1.w + bb1.w);
      *(bf16x8*)(xn + p*LNS + l15*8) = o8;
    }
  }
  __syncthreads();

  // dump xn -> xng[j=c][i=r0+p][ch] (coalesced b128)
  #pragma unroll
  for (int it = 0; it < 4; ++it){
    int idx = tid + it*256;
    int p = idx >> 4, s = idx & 15;
    *(bf16x8*)(xng + ((size_t)c*NN + r0 + p)*DIMC + s*8) = *(const bf16x8*)(xn + p*LNS + s*8);
  }

  const int kofs = lg * 8;
  const int wrow = (wid*32 + l15) * 128;
  const int xrowbase = l15 * LNS;

  // ---- passes 0/1: value*sigmoid(gate) -> Lp / Rp ----
  #pragma unroll
  for (int pr = 0; pr < 2; ++pr){
    const u16* wV = wb + (pr*2 + 0)*16384;
    const u16* wG = wb + (pr*2 + 1)*16384;
    const float* bV = pr ? right_b : left_b;
    const float* bG = pr ? rgate_b : lgate_b;
    u16* dst = pr ? Rp : Lp;

    f32x4 aV[2][4], aG[2][4];
    #pragma unroll
    for (int n = 0; n < 2; ++n)
      #pragma unroll
      for (int pt = 0; pt < 4; ++pt){ aV[n][pt] = {0.f,0.f,0.f,0.f}; aG[n][pt] = {0.f,0.f,0.f,0.f}; }

    #pragma unroll
    for (int ks = 0; ks < 4; ++ks){
      bf16x8 xf[4];
      #pragma unroll
      for (int pt = 0; pt < 4; ++pt)
        xf[pt] = *(const bf16x8*)(xn + xrowbase + pt*16*LNS + ks*32 + kofs);
      #pragma unroll
      for (int n = 0; n < 2; ++n){
        bf16x8 wv = *(const bf16x8*)(wV + wrow + n*16*128 + ks*32 + kofs);
        bf16x8 wg = *(const bf16x8*)(wG + wrow + n*16*128 + ks*32 + kofs);
        #pragma unroll
        for (int pt = 0; pt < 4; ++pt){
          aV[n][pt] = __builtin_amdgcn_mfma_f32_16x16x32_bf16(wv, xf[pt], aV[n][pt], 0, 0, 0);
          aG[n][pt] = __builtin_amdgcn_mfma_f32_16x16x32_bf16(wg, xf[pt], aG[n][pt], 0, 0, 0);
        }
      }
    }
    #pragma unroll
    for (int n = 0; n < 2; ++n){
      int ebase = wid*32 + n*16 + lg*4;
      float4 bv4 = *(const float4*)(bV + ebase);
      float4 bg4 = *(const float4*)(bG + ebase);
      #pragma unroll
      for (int r = 0; r < 4; ++r){
        float bv = r==0?bv4.x : r==1?bv4.y : r==2?bv4.z : bv4.w;
        float bg = r==0?bg4.x : r==1?bg4.y : r==2?bg4.z : bg4.w;
        u16* base = dst + (size_t)(ebase + r)*NPOS + (size_t)c*NN + r0 + l15;
        #pragma unroll
        for (int pt = 0; pt < 4; ++pt){
          float v = (aV[n][pt][r] + bv) * sigm(aG[n][pt][r] + bg);
          base[pt*16] = f2b(v);
        }
      }
    }
  }
}

// ---------------- kernel 2: triangle einsum, BK=64, global_load_lds + XOR swizzle ----------------
// Writes outp TRANSPOSED: outp[d][j][i] (A-operand = Lp rows j, B-operand = Rp rows i).
__global__ __launch_bounds__(256) void phase2_k(const u16* __restrict__ Rp, const u16* __restrict__ Lp,
                                                u16* __restrict__ outp){
  __shared__ u16 lds[17408];
  u16* At = lds;          // holds L rows (j)
  u16* Bt = lds + 8192;   // holds R rows (i)
  const int tid = threadIdx.x, lane = tid & 63, wid = tid >> 6;
  const int bid = blockIdx.x;
  const int d = bid / 9, tile = bid % 9;
  const int i0 = (tile/3)*128, j0 = (tile%3)*128;
  const int wm = wid >> 1, wn = wid & 1;
  const int jw = wm*64, iw = wn*64;   // wave quadrant: rows=j, cols=i
  const int l15 = lane & 15, lg = lane >> 4;
  const int rmask = l15 & 7;

  int srcoff[4];
  #pragma unroll
  for (int cc = 0; cc < 4; ++cc){
    int idx = wid*256 + cc*64 + lane;
    int row = idx >> 3, slot = idx & 7;
    srcoff[cc] = row*NN + ((slot ^ (row & 7)) * 8);
  }

  f32x4 acc[4][4];
  #pragma unroll
  for (int m = 0; m < 4; ++m)
    #pragma unroll
    for (int n = 0; n < 4; ++n) acc[m][n] = {0.f,0.f,0.f,0.f};

  const u16* Lt0 = Lp + (size_t)d*NPOS + (size_t)j0*NN;   // A side
  const u16* Rt0 = Rp + (size_t)d*NPOS + (size_t)i0*NN;   // B side

  for (int k0 = 0; k0 < NN; k0 += 64){
    __syncthreads();
    #pragma unroll
    for (int cc = 0; cc < 4; ++cc){
      glds16(Lt0 + k0 + srcoff[cc], At + (wid*4 + cc)*512);
      glds16(Rt0 + k0 + srcoff[cc], Bt + (wid*4 + cc)*512);
    }
    asm volatile("s_waitcnt vmcnt(0)" ::: "memory");
    __syncthreads();
    #pragma unroll
    for (int ks = 0; ks < 2; ++ks){
      int sl = ((ks*4 + lg) ^ rmask) * 8;
      bf16x8 af[4], bfr[4];
      #pragma unroll
      for (int m = 0; m < 4; ++m)
        af[m] = *(const bf16x8*)(At + (jw + m*16 + l15)*64 + sl);
      #pragma unroll
      for (int n = 0; n < 4; ++n)
        bfr[n] = *(const bf16x8*)(Bt + (iw + n*16 + l15)*64 + sl);
      #pragma unroll
      for (int m = 0; m < 4; ++m)
        #pragma unroll
        for (int n = 0; n < 4; ++n)
          acc[m][n] = __builtin_amdgcn_mfma_f32_16x16x32_bf16(af[m], bfr[n], acc[m][n], 0, 0, 0);
    }
  }

  // epilogue: D[row=j_local][col=i_local]; stage [128][136], store rows of j
  __syncthreads();
  #pragma unroll
  for (int m = 0; m < 4; ++m)
    #pragma unroll
    for (int n = 0; n < 4; ++n)
      #pragma unroll
      for (int r = 0; r < 4; ++r)
        lds[(jw + m*16 + lg*4 + r)*136 + iw + n*16 + l15] = f2b(acc[m][n][r]);
  __syncthreads();
  u16* ob = outp + (size_t)d*NPOS;
  #pragma unroll
  for (int it = 0; it < 8; ++it){
    int idx = tid + it*256;
    int jl = idx >> 4, s = idx & 15;
    *(bf16x8*)(ob + (size_t)(j0 + jl)*NN + i0 + s*8) = *(const bf16x8*)(lds + jl*136 + s*8);
  }
}

// ---------------- kernel 3: LN + ogate GEMM + out-projection + gate ----------------
// block: fixed j, 64 consecutive i (i0..i0+63). outp is [d][j][i] -> contiguous reads.
// ogate computed here: A-frags direct from xng[j][i][ch] (contiguous), B = wO.
__global__ __launch_bounds__(256) void phase3_k(const u16* __restrict__ outp,
    const float* __restrict__ tonw, const float* __restrict__ tonb,
    const u16* __restrict__ wOut, const float* __restrict__ out_b,
    const u16* __restrict__ xng, const u16* __restrict__ wO,
    const float* __restrict__ ogate_b, float* __restrict__ out)
{
  __shared__ u16 xn2[64*132];
  __shared__ float reds[4][64], redq[4][64];
  __shared__ float marr[64], iarr[64];
  const int tid = threadIdx.x, lane = tid & 63, wid = tid >> 6;
  const int bid = blockIdx.x;
  const int j = bid % NN, i0 = (bid / NN) * 64;
  const int l15 = lane & 15, lg = lane >> 4;

  float rv[32];
  float s = 0.f, sq = 0.f;
  #pragma unroll
  for (int q = 0; q < 32; ++q){
    int h = wid*32 + q;
    float v = b2f(outp[(size_t)h*NPOS + (size_t)j*NN + i0 + lane]);
    rv[q] = v; s += v; sq += v*v;
  }
  reds[wid][lane] = s; redq[wid][lane] = sq;
  __syncthreads();
  if (tid < 64){
    float ts = reds[0][tid] + reds[1][tid] + reds[2][tid] + reds[3][tid];
    float tq = redq[0][tid] + redq[1][tid] + redq[2][tid] + redq[3][tid];
    float m  = ts * (1.f/128.f);
    float var = tq * (1.f/128.f) - m*m;
    marr[tid] = m; iarr[tid] = rsqrtf(var + EPSV);
  }
  __syncthreads();
  float m = marr[lane], inv = iarr[lane];
  #pragma unroll
  for (int q = 0; q < 32; ++q){
    int h = wid*32 + q;
    float v = (rv[q] - m)*inv*tonw[h] + tonb[h];
    xn2[lane*132 + h] = f2b(v);
  }
  __syncthreads();

  const int row = wid*16 + l15;
  const int kofs = lg * 8;

  // ---- ogate GEMM: A from global xng (contiguous), B = wO ----
  f32x4 accO[8];
  #pragma unroll
  for (int n = 0; n < 8; ++n) accO[n] = {0.f,0.f,0.f,0.f};
  {
    const u16* xrow = xng + ((size_t)j*NN + i0 + row)*DIMC;
    #pragma unroll
    for (int ks = 0; ks < 4; ++ks){
      bf16x8 af = *(const bf16x8*)(xrow + ks*32 + kofs);
      #pragma unroll
      for (int n = 0; n < 8; ++n){
        bf16x8 bm = *(const bf16x8*)(wO + (n*16 + l15)*128 + ks*32 + kofs);
        accO[n] = __builtin_amdgcn_mfma_f32_16x16x32_bf16(af, bm, accO[n], 0, 0, 0);
      }
    }
  }

  // ---- out-projection GEMM: A from xn2 LDS ----
  f32x4 acc[8];
  #pragma unroll
  for (int n = 0; n < 8; ++n) acc[n] = {0.f,0.f,0.f,0.f};
  #pragma unroll
  for (int ks = 0; ks < 4; ++ks){
    const u16* ap = xn2 + row*132 + ks*32 + kofs;
    bf16x4 a0 = *(const bf16x4*)ap;
    bf16x4 a1 = *(const bf16x4*)(ap + 4);
    bf16x8 af = __builtin_shufflevector(a0, a1, 0,1,2,3,4,5,6,7);
    #pragma unroll
    for (int n = 0; n < 8; ++n){
      bf16x8 bm = *(const bf16x8*)(wOut + (n*16 + l15)*128 + ks*32 + kofs);
      acc[n] = __builtin_amdgcn_mfma_f32_16x16x32_bf16(af, bm, acc[n], 0, 0, 0);
    }
  }

  #pragma unroll
  for (int n = 0; n < 8; ++n){
    int dd = n*16 + l15;
    float bo = out_b[dd];
    float bog = ogate_b[dd];
    #pragma unroll
    for (int r = 0; r < 4; ++r){
      int p = wid*16 + lg*4 + r;
      size_t base = ((size_t)(i0 + p)*NN + j)*DIMC + dd;
      float g = sigm(accO[n][r] + bog);
      out[base] = (acc[n][r] + bo) * g;
    }
  }
}

extern "C" void kernel_launch(void* const* d_in, const int* in_sizes, int n_in,
                              void* d_out, int out_size, void* d_ws, size_t ws_size,
                              hipStream_t stream){
  const float* x       = (const float*)d_in[0];
  const float* norm_w  = (const float*)d_in[1];
  const float* norm_b  = (const float*)d_in[2];
  const float* left_w  = (const float*)d_in[3];
  const float* left_b  = (const float*)d_in[4];
  const float* right_w = (const float*)d_in[5];
  const float* right_b = (const float*)d_in[6];
  const float* lgate_w = (const float*)d_in[7];
  const float* lgate_b = (const float*)d_in[8];
  const float* rgate_w = (const float*)d_in[9];
  const float* rgate_b = (const float*)d_in[10];
  const float* ogate_w = (const float*)d_in[11];
  const float* ogate_b = (const float*)d_in[12];
  const float* ton_w   = (const float*)d_in[13];
  const float* ton_b   = (const float*)d_in[14];
  const float* out_w   = (const float*)d_in[15];
  const float* out_b   = (const float*)d_in[16];

  char* ws = (char*)d_ws;
  const size_t SZ = (size_t)NPOS * DIMC * sizeof(u16);
  u16* Lp   = (u16*)(ws);
  u16* Rp   = (u16*)(ws + SZ);
  u16* xng  = (u16*)(ws + 2*SZ);
  u16* outp = (u16*)(ws + 3*SZ);
  u16* wb   = (u16*)(ws + 4*SZ);

  wconv_k<<<dim3(384), dim3(256), 0, stream>>>(left_w, lgate_w, right_w, rgate_w, ogate_w, out_w, wb);
  proj_k<<<dim3(2304), dim3(256), 0, stream>>>(x, norm_w, norm_b, wb,
      left_b, lgate_b, right_b, rgate_b, Lp, Rp, xng);
  phase2_k<<<dim3(1152), dim3(256), 0, stream>>>(Rp, Lp, outp);
  phase3_k<<<dim3(2304), dim3(256), 0, stream>>>(outp, ton_w, ton_b, wb + 5*16384, out_b,
      xng, wb + 4*16384, ogate_b, (float*)d_out);
}

// Round 11
// 170.387 us; speedup vs baseline: 1.2870x; 1.2870x over previous
//
#include <hip/hip_runtime.h>
#include <stdint.h>

typedef unsigned short u16;
typedef short bf16x8 __attribute__((ext_vector_type(8)));
typedef short bf16x4 __attribute__((ext_vector_type(4)));
typedef float f32x4 __attribute__((ext_vector_type(4)));

#define NN 384
#define DIMC 128
#define NPOS (NN*NN)
#define EPSV 1e-5f
#define LNS 136   // xn LDS row stride in u16

__device__ __forceinline__ u16 f2b(float f){
  union { float f; uint32_t u; } v; v.f = f;
  return (u16)((v.u + 0x7FFFu + ((v.u >> 16) & 1u)) >> 16);
}
__device__ __forceinline__ float b2f(u16 h){
  union { uint32_t u; float f; } v; v.u = ((uint32_t)h) << 16;
  return v.f;
}
__device__ __forceinline__ float sigm(float z){
  return __builtin_amdgcn_rcpf(1.0f + __expf(-z));
}

__device__ __forceinline__ void glds16(const u16* g, u16* l){
  __builtin_amdgcn_global_load_lds((const __attribute__((address_space(1))) void*)(g),
                                   (__attribute__((address_space(3))) void*)(l), 16, 0, 0);
}

// ---------------- kernel 0: fp32 -> bf16 weight conversion ----------------
__global__ void wconv_k(const float* __restrict__ s0, const float* __restrict__ s1,
                        const float* __restrict__ s2, const float* __restrict__ s3,
                        const float* __restrict__ s4, const float* __restrict__ s5,
                        u16* __restrict__ dst){
  int bid = blockIdx.x;
  int m = bid >> 6;
  int off = ((bid & 63) << 8) + threadIdx.x;
  const float* src = s0;
  if (m==1) src=s1; else if (m==2) src=s2; else if (m==3) src=s3;
  else if (m==4) src=s4; else if (m==5) src=s5;
  dst[(m<<14) + off] = f2b(src[off]);
}

// ---------------- kernel 1: LN + 5 projections ----------------
// block: fixed second-index c (j), 64 first-index rows r0..r0+63 (i), 4 waves.
// LN: 16 lanes per position, 8 channels per lane, 4-level shfl reduce.
// L/R passes: mfma(A=w, B=xn) -> D[e][p]; direct coalesced stores -> [e][j][k=i].
// O pass: mfma(A=w, B=xn) -> D[e][p]; LDS-transpose (reusing xn) -> gate[i][j][e].
__global__ __launch_bounds__(256) void proj_k(
    const float* __restrict__ x, const float* __restrict__ nw, const float* __restrict__ nb,
    const u16* __restrict__ wb,
    const float* __restrict__ left_b, const float* __restrict__ lgate_b,
    const float* __restrict__ right_b, const float* __restrict__ rgate_b,
    const float* __restrict__ ogate_b,
    u16* __restrict__ Lp, u16* __restrict__ Rp, u16* __restrict__ gate)
{
  __shared__ u16 xn[64*LNS];     // 17408 B (reused as transpose buffer in O pass)
  const int tid = threadIdx.x, lane = tid & 63, wid = tid >> 6;
  const int bid = blockIdx.x;
  const int c = bid % NN, r0 = (bid / NN) * 64;
  const int l15 = lane & 15, lg = lane >> 4;

  // ---- LN: 16 lanes per position, 8 ch each ----
  {
    float4 w0 = *(const float4*)(nw + l15*8);
    float4 w1 = *(const float4*)(nw + l15*8 + 4);
    float4 bb0 = *(const float4*)(nb + l15*8);
    float4 bb1 = *(const float4*)(nb + l15*8 + 4);
    float4 v0[4], v1[4];
    #pragma unroll
    for (int it = 0; it < 4; ++it){
      int p = wid*16 + it*4 + lg;
      const float* xp = x + ((size_t)(r0 + p)*NN + c)*DIMC + l15*8;
      v0[it] = *(const float4*)xp;
      v1[it] = *(const float4*)(xp + 4);
    }
    #pragma unroll
    for (int it = 0; it < 4; ++it){
      int p = wid*16 + it*4 + lg;
      float s  = (v0[it].x+v0[it].y)+(v0[it].z+v0[it].w)+((v1[it].x+v1[it].y)+(v1[it].z+v1[it].w));
      float sq = v0[it].x*v0[it].x+v0[it].y*v0[it].y+v0[it].z*v0[it].z+v0[it].w*v0[it].w
               + v1[it].x*v1[it].x+v1[it].y*v1[it].y+v1[it].z*v1[it].z+v1[it].w*v1[it].w;
      #pragma unroll
      for (int o = 8; o; o >>= 1){ s += __shfl_xor(s, o); sq += __shfl_xor(sq, o); }
      float mean = s * (1.0f/128.0f);
      float var  = sq * (1.0f/128.0f) - mean*mean;
      float inv  = rsqrtf(var + EPSV);
      bf16x8 o8;
      o8[0] = (short)f2b((v0[it].x - mean)*inv*w0.x + bb0.x);
      o8[1] = (short)f2b((v0[it].y - mean)*inv*w0.y + bb0.y);
      o8[2] = (short)f2b((v0[it].z - mean)*inv*w0.z + bb0.z);
      o8[3] = (short)f2b((v0[it].w - mean)*inv*w0.w + bb0.w);
      o8[4] = (short)f2b((v1[it].x - mean)*inv*w1.x + bb1.x);
      o8[5] = (short)f2b((v1[it].y - mean)*inv*w1.y + bb1.y);
      o8[6] = (short)f2b((v1[it].z - mean)*inv*w1.z + bb1.z);
      o8[7] = (short)f2b((v1[it].w - mean)*inv*w1.w + bb1.w);
      *(bf16x8*)(xn + p*LNS + l15*8) = o8;
    }
  }
  __syncthreads();

  const int kofs = lg * 8;
  const int wrow = (wid*32 + l15) * 128;
  const int xrowbase = l15 * LNS;

  // ---- passes 0/1: value*sigmoid(gate) -> Lp / Rp ----
  #pragma unroll
  for (int pr = 0; pr < 2; ++pr){
    const u16* wV = wb + (pr*2 + 0)*16384;
    const u16* wG = wb + (pr*2 + 1)*16384;
    const float* bV = pr ? right_b : left_b;
    const float* bG = pr ? rgate_b : lgate_b;
    u16* dst = pr ? Rp : Lp;

    f32x4 aV[2][4], aG[2][4];
    #pragma unroll
    for (int n = 0; n < 2; ++n)
      #pragma unroll
      for (int pt = 0; pt < 4; ++pt){ aV[n][pt] = {0.f,0.f,0.f,0.f}; aG[n][pt] = {0.f,0.f,0.f,0.f}; }

    #pragma unroll
    for (int ks = 0; ks < 4; ++ks){
      bf16x8 xf[4];
      #pragma unroll
      for (int pt = 0; pt < 4; ++pt)
        xf[pt] = *(const bf16x8*)(xn + xrowbase + pt*16*LNS + ks*32 + kofs);
      #pragma unroll
      for (int n = 0; n < 2; ++n){
        bf16x8 wv = *(const bf16x8*)(wV + wrow + n*16*128 + ks*32 + kofs);
        bf16x8 wg = *(const bf16x8*)(wG + wrow + n*16*128 + ks*32 + kofs);
        #pragma unroll
        for (int pt = 0; pt < 4; ++pt){
          aV[n][pt] = __builtin_amdgcn_mfma_f32_16x16x32_bf16(wv, xf[pt], aV[n][pt], 0, 0, 0);
          aG[n][pt] = __builtin_amdgcn_mfma_f32_16x16x32_bf16(wg, xf[pt], aG[n][pt], 0, 0, 0);
        }
      }
    }
    #pragma unroll
    for (int n = 0; n < 2; ++n){
      int ebase = wid*32 + n*16 + lg*4;
      float4 bv4 = *(const float4*)(bV + ebase);
      float4 bg4 = *(const float4*)(bG + ebase);
      #pragma unroll
      for (int r = 0; r < 4; ++r){
        float bv = r==0?bv4.x : r==1?bv4.y : r==2?bv4.z : bv4.w;
        float bg = r==0?bg4.x : r==1?bg4.y : r==2?bg4.z : bg4.w;
        u16* base = dst + (size_t)(ebase + r)*NPOS + (size_t)c*NN + r0 + l15;
        #pragma unroll
        for (int pt = 0; pt < 4; ++pt){
          float v = (aV[n][pt][r] + bv) * sigm(aG[n][pt][r] + bg);
          base[pt*16] = f2b(v);
        }
      }
    }
  }

  // ---- pass 2: ogate -> sigmoid -> gate[i][j][e] via LDS transpose (reuse xn) ----
  {
    const u16* wO = wb + 4*16384;
    f32x4 aO[2][4];
    #pragma unroll
    for (int n = 0; n < 2; ++n)
      #pragma unroll
      for (int pt = 0; pt < 4; ++pt) aO[n][pt] = {0.f,0.f,0.f,0.f};

    #pragma unroll
    for (int ks = 0; ks < 4; ++ks){
      bf16x8 xf[4];
      #pragma unroll
      for (int pt = 0; pt < 4; ++pt)
        xf[pt] = *(const bf16x8*)(xn + xrowbase + pt*16*LNS + ks*32 + kofs);
      #pragma unroll
      for (int n = 0; n < 2; ++n){
        bf16x8 wo = *(const bf16x8*)(wO + wrow + n*16*128 + ks*32 + kofs);
        #pragma unroll
        for (int pt = 0; pt < 4; ++pt)
          aO[n][pt] = __builtin_amdgcn_mfma_f32_16x16x32_bf16(wo, xf[pt], aO[n][pt], 0, 0, 0);
      }
    }
    __syncthreads();   // all waves done reading xn -> safe to overwrite
    #pragma unroll
    for (int n = 0; n < 2; ++n){
      int ebase = wid*32 + n*16 + lg*4;
      float4 bo4 = *(const float4*)(ogate_b + ebase);
      #pragma unroll
      for (int r = 0; r < 4; ++r){
        float bo = r==0?bo4.x : r==1?bo4.y : r==2?bo4.z : bo4.w;
        #pragma unroll
        for (int pt = 0; pt < 4; ++pt)
          xn[(pt*16 + l15)*LNS + ebase + r] = f2b(sigm(aO[n][pt][r] + bo));
      }
    }
    __syncthreads();
    #pragma unroll
    for (int it = 0; it < 4; ++it){
      int idx = tid + it*256;
      int p = idx >> 4, s = idx & 15;
      *(bf16x8*)(gate + ((size_t)(r0 + p)*NN + c)*DIMC + s*8) = *(const bf16x8*)(xn + p*LNS + s*8);
    }
  }
}

// ---------------- kernel 2: triangle einsum, BK=64, global_load_lds + XOR swizzle ----------------
// XCD-aware block remap: all 9 tiles of one d stay on one XCD (panel reuse in its L2).
__global__ __launch_bounds__(256) void phase2_k(const u16* __restrict__ Rp, const u16* __restrict__ Lp,
                                                u16* __restrict__ outp){
  __shared__ u16 lds[17408];
  u16* At = lds;
  u16* Bt = lds + 8192;
  const int tid = threadIdx.x, lane = tid & 63, wid = tid >> 6;
  const int bid = blockIdx.x;
  // bijective remap: 1152 = 8 XCDs x 16 d x 9 tiles
  const int xcd = bid & 7, kk = bid >> 3;
  const int d = xcd*16 + kk/9, tile = kk % 9;
  const int i0 = (tile/3)*128, j0 = (tile%3)*128;
  const int wm = wid >> 1, wn = wid & 1;
  const int iw = wm*64, jw = wn*64;
  const int l15 = lane & 15, lg = lane >> 4;
  const int rmask = l15 & 7;

  int srcoff[4];
  #pragma unroll
  for (int cc = 0; cc < 4; ++cc){
    int idx = wid*256 + cc*64 + lane;
    int row = idx >> 3, slot = idx & 7;
    srcoff[cc] = row*NN + ((slot ^ (row & 7)) * 8);
  }

  f32x4 acc[4][4];
  #pragma unroll
  for (int m = 0; m < 4; ++m)
    #pragma unroll
    for (int n = 0; n < 4; ++n) acc[m][n] = {0.f,0.f,0.f,0.f};

  const u16* Rt0 = Rp + (size_t)d*NPOS + (size_t)i0*NN;
  const u16* Lt0 = Lp + (size_t)d*NPOS + (size_t)j0*NN;

  for (int k0 = 0; k0 < NN; k0 += 64){
    __syncthreads();
    #pragma unroll
    for (int cc = 0; cc < 4; ++cc){
      glds16(Rt0 + k0 + srcoff[cc], At + (wid*4 + cc)*512);
      glds16(Lt0 + k0 + srcoff[cc], Bt + (wid*4 + cc)*512);
    }
    asm volatile("s_waitcnt vmcnt(0)" ::: "memory");
    __syncthreads();
    #pragma unroll
    for (int ks = 0; ks < 2; ++ks){
      int sl = ((ks*4 + lg) ^ rmask) * 8;
      bf16x8 af[4], bfr[4];
      #pragma unroll
      for (int m = 0; m < 4; ++m)
        af[m] = *(const bf16x8*)(At + (iw + m*16 + l15)*64 + sl);
      #pragma unroll
      for (int n = 0; n < 4; ++n)
        bfr[n] = *(const bf16x8*)(Bt + (jw + n*16 + l15)*64 + sl);
      #pragma unroll
      for (int m = 0; m < 4; ++m)
        #pragma unroll
        for (int n = 0; n < 4; ++n)
          acc[m][n] = __builtin_amdgcn_mfma_f32_16x16x32_bf16(af[m], bfr[n], acc[m][n], 0, 0, 0);
    }
  }

  __syncthreads();
  #pragma unroll
  for (int m = 0; m < 4; ++m)
    #pragma unroll
    for (int n = 0; n < 4; ++n)
      #pragma unroll
      for (int r = 0; r < 4; ++r)
        lds[(iw + m*16 + lg*4 + r)*136 + jw + n*16 + l15] = f2b(acc[m][n][r]);
  __syncthreads();
  u16* ob = outp + (size_t)d*NPOS;
  #pragma unroll
  for (int it = 0; it < 8; ++it){
    int idx = tid + it*256;
    int i = idx >> 4, s = idx & 15;
    *(bf16x8*)(ob + (size_t)(i0 + i)*NN + j0 + s*8) = *(const bf16x8*)(lds + i*136 + s*8);
  }
}

// ---------------- kernel 3: LN + out-projection + gate ----------------
// block: fixed i, 64 consecutive j. gate layout [i][j][e] -> 32B-run reads.
__global__ __launch_bounds__(256) void phase3_k(const u16* __restrict__ outp,
    const float* __restrict__ tonw, const float* __restrict__ tonb,
    const u16* __restrict__ wOut, const float* __restrict__ out_b,
    const u16* __restrict__ gate, float* __restrict__ out)
{
  __shared__ u16 xn2[64*132];
  __shared__ float reds[4][64], redq[4][64];
  __shared__ float marr[64], iarr[64];
  const int tid = threadIdx.x, lane = tid & 63, wid = tid >> 6;
  const int bid = blockIdx.x;
  const int i = bid % NN, j0 = (bid / NN) * 64;
  const int l15 = lane & 15, lg = lane >> 4;

  float rv[32];
  float s = 0.f, sq = 0.f;
  #pragma unroll
  for (int q = 0; q < 32; ++q){
    int h = wid*32 + q;
    float v = b2f(outp[(size_t)h*NPOS + (size_t)i*NN + j0 + lane]);
    rv[q] = v; s += v; sq += v*v;
  }
  reds[wid][lane] = s; redq[wid][lane] = sq;
  __syncthreads();
  if (tid < 64){
    float ts = reds[0][tid] + reds[1][tid] + reds[2][tid] + reds[3][tid];
    float tq = redq[0][tid] + redq[1][tid] + redq[2][tid] + redq[3][tid];
    float m  = ts * (1.f/128.f);
    float var = tq * (1.f/128.f) - m*m;
    marr[tid] = m; iarr[tid] = rsqrtf(var + EPSV);
  }
  __syncthreads();
  float m = marr[lane], inv = iarr[lane];
  #pragma unroll
  for (int q = 0; q < 32; ++q){
    int h = wid*32 + q;
    float v = (rv[q] - m)*inv*tonw[h] + tonb[h];
    xn2[lane*132 + h] = f2b(v);
  }
  __syncthreads();

  f32x4 acc[8];
  #pragma unroll
  for (int n = 0; n < 8; ++n) acc[n] = {0.f,0.f,0.f,0.f};
  const int row = wid*16 + l15;
  const int kofs = lg * 8;
  #pragma unroll
  for (int ks = 0; ks < 4; ++ks){
    const u16* ap = xn2 + row*132 + ks*32 + kofs;
    bf16x4 a0 = *(const bf16x4*)ap;
    bf16x4 a1 = *(const bf16x4*)(ap + 4);
    bf16x8 af = __builtin_shufflevector(a0, a1, 0,1,2,3,4,5,6,7);
    #pragma unroll
    for (int n = 0; n < 8; ++n){
      bf16x8 bm = *(const bf16x8*)(wOut + (n*16 + l15)*128 + ks*32 + kofs);
      acc[n] = __builtin_amdgcn_mfma_f32_16x16x32_bf16(af, bm, acc[n], 0, 0, 0);
    }
  }
  #pragma unroll
  for (int n = 0; n < 8; ++n){
    int dd = n*16 + l15;
    float bo = out_b[dd];
    #pragma unroll
    for (int r = 0; r < 4; ++r){
      int p = wid*16 + lg*4 + r;
      size_t base = ((size_t)i*NN + j0 + p)*DIMC + dd;
      float g = b2f(gate[base]);
      out[base] = (acc[n][r] + bo) * g;
    }
  }
}

extern "C" void kernel_launch(void* const* d_in, const int* in_sizes, int n_in,
                              void* d_out, int out_size, void* d_ws, size_t ws_size,
                              hipStream_t stream){
  const float* x       = (const float*)d_in[0];
  const float* norm_w  = (const float*)d_in[1];
  const float* norm_b  = (const float*)d_in[2];
  const float* left_w  = (const float*)d_in[3];
  const float* left_b  = (const float*)d_in[4];
  const float* right_w = (const float*)d_in[5];
  const float* right_b = (const float*)d_in[6];
  const float* lgate_w = (const float*)d_in[7];
  const float* lgate_b = (const float*)d_in[8];
  const float* rgate_w = (const float*)d_in[9];
  const float* rgate_b = (const float*)d_in[10];
  const float* ogate_w = (const float*)d_in[11];
  const float* ogate_b = (const float*)d_in[12];
  const float* ton_w   = (const float*)d_in[13];
  const float* ton_b   = (const float*)d_in[14];
  const float* out_w   = (const float*)d_in[15];
  const float* out_b   = (const float*)d_in[16];

  char* ws = (char*)d_ws;
  const size_t SZ = (size_t)NPOS * DIMC * sizeof(u16);
  u16* Lp   = (u16*)(ws);
  u16* Rp   = (u16*)(ws + SZ);
  u16* gate = (u16*)(ws + 2*SZ);
  u16* outp = (u16*)(ws + 3*SZ);
  u16* wb   = (u16*)(ws + 4*SZ);

  wconv_k<<<dim3(384), dim3(256), 0, stream>>>(left_w, lgate_w, right_w, rgate_w, ogate_w, out_w, wb);
  proj_k<<<dim3(2304), dim3(256), 0, stream>>>(x, norm_w, norm_b, wb,
      left_b, lgate_b, right_b, rgate_b, ogate_b, Lp, Rp, gate);
  phase2_k<<<dim3(1152), dim3(256), 0, stream>>>(Rp, Lp, outp);
  phase3_k<<<dim3(2304), dim3(256), 0, stream>>>(outp, ton_w, ton_b, wb + 5*16384, out_b, gate, (float*)d_out);
}